// Round 2
// 1420.915 us; speedup vs baseline: 1.3886x; 1.3886x over previous
//
#include <hip/hip_runtime.h>

#define HID 128

typedef __bf16 bf16x8 __attribute__((ext_vector_type(8)));
typedef float f32x4 __attribute__((ext_vector_type(4)));

__device__ __forceinline__ unsigned short f2bf(float x) {
  unsigned int u = __builtin_bit_cast(unsigned int, x);
  u += 0x7FFFu + ((u >> 16) & 1u);
  return (unsigned short)(u >> 16);
}

__global__ void zero_int_kernel(int* __restrict__ p, int n) {
  int i = blockIdx.x * blockDim.x + threadIdx.x;
  if (i < n) p[i] = 0;
}

__global__ void degree_kernel(const int* __restrict__ dst, int* __restrict__ deg, int n) {
  int i = blockIdx.x * blockDim.x + threadIdx.x;
  if (i < n) atomicAdd(&deg[dst[i]], 1);
}

// single-block exclusive scan over deg[0..n) -> eoff[0..n]
__global__ void __launch_bounds__(1024) scan_kernel(const int* __restrict__ deg,
                                                    int* __restrict__ eoff, int n) {
  __shared__ int ssum[1024];
  int t = threadIdx.x;
  int chunk = (n + 1023) / 1024;
  int beg = t * chunk;
  int end = min(beg + chunk, n);
  int s = 0;
  for (int i = beg; i < end; ++i) s += deg[i];
  ssum[t] = s;
  __syncthreads();
  for (int off = 1; off < 1024; off <<= 1) {
    int v = (t >= off) ? ssum[t - off] : 0;
    __syncthreads();
    ssum[t] += v;
    __syncthreads();
  }
  int base = (t == 0) ? 0 : ssum[t - 1];
  for (int i = beg; i < end; ++i) { eoff[i] = base; base += deg[i]; }
  if (t == 1023) eoff[n] = base;
}

__global__ void copy_int_kernel(const int* __restrict__ src, int* __restrict__ dst, int n) {
  int i = blockIdx.x * blockDim.x + threadIdx.x;
  if (i < n) dst[i] = src[i];
}

// Materialize the CSR payload directly in sorted order: per in-edge slot,
// store src id and {ppi, self} weights.  Removes the esort->esrc/ppi/selfw
// random-indirection chain from the hot aggregate loop.
__global__ void scatter_kernel(const int* __restrict__ edst, const int* __restrict__ esrc,
                               const float* __restrict__ ppi, const float* __restrict__ selfw,
                               int* __restrict__ cursor,
                               int* __restrict__ esrc_s, float2* __restrict__ w2, int n) {
  int i = blockIdx.x * blockDim.x + threadIdx.x;
  if (i < n) {
    int d = edst[i];
    int pos = atomicAdd(&cursor[d], 1);
    esrc_s[pos] = esrc[i];
    w2[pos] = make_float2(ppi[i], selfw[i]);
  }
}

// one block (128 thr) per node: h0[node][t] = relu(sum_bag fw*emb[id][t] + bias[t])
// 8-way unrolled: ids/fw are sequential streams; 8 independent emb-row gathers in flight.
__global__ void __launch_bounds__(128) embed_kernel(const int* __restrict__ ids,
                                                    const int* __restrict__ offs,
                                                    const float* __restrict__ fw,
                                                    const float* __restrict__ emb,
                                                    const float* __restrict__ bias,
                                                    float* __restrict__ h) {
  int node = blockIdx.x;
  int t = threadIdx.x;
  int beg = offs[node], end = offs[node + 1];
  float acc = 0.f;
  int i = beg;
  for (; i + 8 <= end; i += 8) {
    int id[8];
    float w[8];
    float v[8];
#pragma unroll
    for (int u = 0; u < 8; ++u) id[u] = ids[i + u];
#pragma unroll
    for (int u = 0; u < 8; ++u) w[u] = fw[i + u];
#pragma unroll
    for (int u = 0; u < 8; ++u) v[u] = emb[(long)id[u] * HID + t];
#pragma unroll
    for (int u = 0; u < 8; ++u) acc += w[u] * v[u];
  }
  for (; i < end; ++i) {
    acc += fw[i] * emb[(long)ids[i] * HID + t];
  }
  acc += bias[t];
  h[(long)node * HID + t] = acc > 0.f ? acc : 0.f;
}

// one block (128 thr) per dst node: accumulate agg (ppi) and res (self) over CSR in-edges.
// Sorted payload (esrc_s/w2) => sequential index/weight streams; 8 independent
// h-row gathers in flight per wave (latency-bound fix; was a 3-deep serial chain).
__global__ void __launch_bounds__(128) aggregate_kernel(const float* __restrict__ h,
                                                        const int* __restrict__ eoff,
                                                        const int* __restrict__ esrc_s,
                                                        const float2* __restrict__ w2,
                                                        float* __restrict__ agg,
                                                        float* __restrict__ res) {
  int node = blockIdx.x;
  int t = threadIdx.x;
  int beg = eoff[node], end = eoff[node + 1];
  float a = 0.f, r = 0.f;
  int j = beg;
  for (; j + 8 <= end; j += 8) {
    int s[8];
    float2 w[8];
    float v[8];
#pragma unroll
    for (int u = 0; u < 8; ++u) s[u] = esrc_s[j + u];
#pragma unroll
    for (int u = 0; u < 8; ++u) w[u] = w2[j + u];
#pragma unroll
    for (int u = 0; u < 8; ++u) v[u] = h[(long)s[u] * HID + t];
#pragma unroll
    for (int u = 0; u < 8; ++u) { a += w[u].x * v[u]; r += w[u].y * v[u]; }
  }
  for (; j < end; ++j) {
    int s = esrc_s[j];
    float2 w = w2[j];
    float v = h[(long)s * HID + t];
    a += w.x * v;
    r += w.y * v;
  }
  agg[(long)node * HID + t] = a;
  res[(long)node * HID + t] = r;
}

// hout[node][t] = relu(agg[node]@W + b)[t] + res[node][t] ; W cached in LDS (f32, exact)
__global__ void __launch_bounds__(256) update_kernel(const float* __restrict__ agg,
                                                     const float* __restrict__ res,
                                                     const float* __restrict__ W,
                                                     const float* __restrict__ b,
                                                     float* __restrict__ hout, int n_nodes) {
  __shared__ __align__(16) float sW[HID * HID];
  __shared__ float sx[2][HID];
  int t = threadIdx.x & (HID - 1);
  int sub = threadIdx.x >> 7;
  for (int i = threadIdx.x; i < HID * HID / 4; i += 256)
    ((float4*)sW)[i] = ((const float4*)W)[i];
  float bias = b[t];
  __syncthreads();
  for (int node0 = blockIdx.x * 2; node0 < n_nodes; node0 += gridDim.x * 2) {
    int node = node0 + sub;
    bool valid = node < n_nodes;
    if (valid) sx[sub][t] = agg[(long)node * HID + t];
    __syncthreads();
    if (valid) {
      float acc = 0.f;
#pragma unroll 16
      for (int k = 0; k < HID; ++k) acc += sx[sub][k] * sW[k * HID + t];
      float v = acc + bias;
      v = v > 0.f ? v : 0.f;
      hout[(long)node * HID + t] = v + res[(long)node * HID + t];
    }
    __syncthreads();
  }
}

// WoT[n][k] = bf16(Wo[k][n])
__global__ void transpose_wo_kernel(const float* __restrict__ Wo,
                                    unsigned short* __restrict__ WoT, int labels) {
  int idx = blockIdx.x * 256 + threadIdx.x;
  if (idx < labels * HID) {
    int n = idx >> 7, k = idx & (HID - 1);
    WoT[idx] = f2bf(Wo[(long)k * labels + n]);
  }
}

#define LDK 136  // padded LDS K-stride (shorts); 272B rows keep 16B alignment, break bank aliasing

// out[50000 x labels] = h @ Wo + bo, bf16 MFMA, f32 accumulate.
// block = 256 thr = 4 waves; block tile 64(M) x 80(N); full K=128 staged once.
__global__ void __launch_bounds__(256) out_gemm_kernel(const float* __restrict__ h,
                                                       const unsigned short* __restrict__ WoT,
                                                       const float* __restrict__ bo,
                                                       float* __restrict__ out,
                                                       int n_nodes, int labels) {
  __shared__ __align__(16) unsigned short sA[64 * LDK];
  __shared__ __align__(16) unsigned short sB[80 * LDK];
  int m0 = blockIdx.x * 64;
  int n0 = blockIdx.y * 80;
  int tid = threadIdx.x;

  // stage A: 64 rows x 128 cols of h, f32 -> bf16
  for (int i = tid; i < 64 * 32; i += 256) {
    int r = i >> 5, c4 = i & 31;
    int row = m0 + r;
    if (row >= n_nodes) row = n_nodes - 1;  // clamp: loads valid, stores bounded later
    float4 v = ((const float4*)(h + (long)row * HID))[c4];
    ushort4 bb;
    bb.x = f2bf(v.x); bb.y = f2bf(v.y); bb.z = f2bf(v.z); bb.w = f2bf(v.w);
    *(ushort4*)&sA[r * LDK + c4 * 4] = bb;
  }
  // stage B: 80 rows (n) x 128 cols (k) of WoT (already bf16)
  for (int i = tid; i < 80 * 32; i += 256) {
    int r = i >> 5, c4 = i & 31;
    ushort4 v = ((const ushort4*)(WoT + (long)(n0 + r) * HID))[c4];
    *(ushort4*)&sB[r * LDK + c4 * 4] = v;
  }
  __syncthreads();

  int wave = tid >> 6, lane = tid & 63;
  int lrow = lane & 15, quad = lane >> 4;
  f32x4 acc[5];
#pragma unroll
  for (int c = 0; c < 5; ++c) acc[c] = (f32x4){0.f, 0.f, 0.f, 0.f};

#pragma unroll
  for (int kk = 0; kk < 4; ++kk) {
    bf16x8 af = *(const bf16x8*)&sA[(wave * 16 + lrow) * LDK + kk * 32 + quad * 8];
#pragma unroll
    for (int c = 0; c < 5; ++c) {
      bf16x8 bf = *(const bf16x8*)&sB[(c * 16 + lrow) * LDK + kk * 32 + quad * 8];
      acc[c] = __builtin_amdgcn_mfma_f32_16x16x32_bf16(af, bf, acc[c], 0, 0, 0);
    }
  }

  // epilogue: D mapping col = lane&15, row = quad*4 + reg
#pragma unroll
  for (int c = 0; c < 5; ++c) {
    int n = n0 + c * 16 + lrow;
    float bias = bo[n];
#pragma unroll
    for (int r = 0; r < 4; ++r) {
      int m = m0 + wave * 16 + quad * 4 + r;
      if (m < n_nodes) out[(long)m * labels + n] = acc[c][r] + bias;
    }
  }
}

extern "C" void kernel_launch(void* const* d_in, const int* in_sizes, int n_in,
                              void* d_out, int out_size, void* d_ws, size_t ws_size,
                              hipStream_t stream) {
  const int* feat_ids = (const int*)d_in[0];
  const int* offsets = (const int*)d_in[1];
  const float* feat_w = (const float*)d_in[2];
  const int* esrc = (const int*)d_in[3];
  const int* edst = (const int*)d_in[4];
  const float* ppi = (const float*)d_in[5];
  const float* selfw = (const float*)d_in[6];
  const float* emb = (const float*)d_in[7];
  const float* ibias = (const float*)d_in[8];
  const float* W1 = (const float*)d_in[9];
  const float* b1 = (const float*)d_in[10];
  const float* W2 = (const float*)d_in[11];
  const float* b2 = (const float*)d_in[12];
  const float* Wo = (const float*)d_in[13];
  const float* bo = (const float*)d_in[14];
  float* out = (float*)d_out;

  int N = in_sizes[1] - 1;       // 50000
  int E = in_sizes[3];           // 1600000
  int LABELS = in_sizes[14];     // 2000

  char* ws = (char*)d_ws;
  size_t HN = (size_t)N * HID;
  float* h0 = (float*)ws;                    ws += HN * 4;
  float* agg = (float*)ws;                   ws += HN * 4;
  float* res = (float*)ws;                   ws += HN * 4;
  unsigned short* WoT = (unsigned short*)ws; ws += (size_t)LABELS * HID * 2;
  float2* w2 = (float2*)ws;                  ws += (size_t)E * 8;   // 8B-aligned here
  int* deg = (int*)ws;                       ws += (size_t)N * 4;
  int* eoff = (int*)ws;                      ws += (size_t)(N + 1) * 4;
  int* cursor = (int*)ws;                    ws += (size_t)N * 4;
  int* esrc_s = (int*)ws;                    ws += (size_t)E * 4;

  // build dst-CSR with payload sorted in place (reused by both layers)
  zero_int_kernel<<<(N + 255) / 256, 256, 0, stream>>>(deg, N);
  degree_kernel<<<(E + 255) / 256, 256, 0, stream>>>(edst, deg, E);
  scan_kernel<<<1, 1024, 0, stream>>>(deg, eoff, N);
  copy_int_kernel<<<(N + 255) / 256, 256, 0, stream>>>(eoff, cursor, N);
  scatter_kernel<<<(E + 255) / 256, 256, 0, stream>>>(edst, esrc, ppi, selfw,
                                                      cursor, esrc_s, w2, E);

  // input layer
  embed_kernel<<<N, HID, 0, stream>>>(feat_ids, offsets, feat_w, emb, ibias, h0);
  transpose_wo_kernel<<<(LABELS * HID + 255) / 256, 256, 0, stream>>>(Wo, WoT, LABELS);

  // GCN layer 1
  aggregate_kernel<<<N, HID, 0, stream>>>(h0, eoff, esrc_s, w2, agg, res);
  update_kernel<<<1024, 256, 0, stream>>>(agg, res, W1, b1, h0, N);
  // GCN layer 2
  aggregate_kernel<<<N, HID, 0, stream>>>(h0, eoff, esrc_s, w2, agg, res);
  update_kernel<<<1024, 256, 0, stream>>>(agg, res, W2, b2, h0, N);

  // output layer
  dim3 g((N + 63) / 64, LABELS / 80);
  out_gemm_kernel<<<g, 256, 0, stream>>>(h0, WoT, bo, out, N, LABELS);
}

// Round 3
// 1281.477 us; speedup vs baseline: 1.5397x; 1.1088x over previous
//
#include <hip/hip_runtime.h>

#define HID 128

typedef __bf16 bf16x8 __attribute__((ext_vector_type(8)));
typedef float f32x4 __attribute__((ext_vector_type(4)));

__device__ __forceinline__ unsigned short f2bf(float x) {
  unsigned int u = __builtin_bit_cast(unsigned int, x);
  u += 0x7FFFu + ((u >> 16) & 1u);
  return (unsigned short)(u >> 16);
}
__device__ __forceinline__ float bf2f(unsigned short x) {
  return __builtin_bit_cast(float, (unsigned int)x << 16);
}

__global__ void zero_int_kernel(int* __restrict__ p, int n) {
  int i = blockIdx.x * blockDim.x + threadIdx.x;
  if (i < n) p[i] = 0;
}

__global__ void degree_kernel(const int* __restrict__ dst, int* __restrict__ deg, int n) {
  int i = blockIdx.x * blockDim.x + threadIdx.x;
  if (i < n) atomicAdd(&deg[dst[i]], 1);
}

// single-block exclusive scan over deg[0..n) -> eoff[0..n]
__global__ void __launch_bounds__(1024) scan_kernel(const int* __restrict__ deg,
                                                    int* __restrict__ eoff, int n) {
  __shared__ int ssum[1024];
  int t = threadIdx.x;
  int chunk = (n + 1023) / 1024;
  int beg = t * chunk;
  int end = min(beg + chunk, n);
  int s = 0;
  for (int i = beg; i < end; ++i) s += deg[i];
  ssum[t] = s;
  __syncthreads();
  for (int off = 1; off < 1024; off <<= 1) {
    int v = (t >= off) ? ssum[t - off] : 0;
    __syncthreads();
    ssum[t] += v;
    __syncthreads();
  }
  int base = (t == 0) ? 0 : ssum[t - 1];
  for (int i = beg; i < end; ++i) { eoff[i] = base; base += deg[i]; }
  if (t == 1023) eoff[n] = base;
}

__global__ void copy_int_kernel(const int* __restrict__ src, int* __restrict__ dst, int n) {
  int i = blockIdx.x * blockDim.x + threadIdx.x;
  if (i < n) dst[i] = src[i];
}

// CSR payload materialized in sorted order, one 16B record per edge:
// {src, ppi_bits, self_bits, pad}.  One dwordx4 store here; one broadcast
// dwordx4 load per edge in aggregate.
__global__ void scatter_kernel(const int* __restrict__ edst, const int* __restrict__ esrc,
                               const float* __restrict__ ppi, const float* __restrict__ selfw,
                               int* __restrict__ cursor, int4* __restrict__ edges, int n) {
  int i = blockIdx.x * blockDim.x + threadIdx.x;
  if (i < n) {
    int d = edst[i];
    int pos = atomicAdd(&cursor[d], 1);
    edges[pos] = make_int4(esrc[i], __builtin_bit_cast(int, ppi[i]),
                           __builtin_bit_cast(int, selfw[i]), 0);
  }
}

// emb table f32 -> bf16 (one-time, 30MB traffic)
__global__ void cast_emb_kernel(const float* __restrict__ emb,
                                unsigned short* __restrict__ embb, int n) {
  int i = blockIdx.x * blockDim.x + threadIdx.x;
  if (i < n) embb[i] = f2bf(emb[i]);
}

// wave-per-node embed: lane u covers cols {2u, 2u+1} via one packed-uint bf16x2
// gather (256B/row per wave).  4 nodes per 256-thr block.  f32 accumulate,
// bf16 h output.
__global__ void __launch_bounds__(256) embed_kernel(const int* __restrict__ ids,
                                                    const int* __restrict__ offs,
                                                    const float* __restrict__ fw,
                                                    const unsigned int* __restrict__ embb,
                                                    const float* __restrict__ bias,
                                                    unsigned int* __restrict__ hb, int n_nodes) {
  int node = blockIdx.x * 4 + (threadIdx.x >> 6);
  if (node >= n_nodes) return;
  int u = threadIdx.x & 63;
  int beg = offs[node], end = offs[node + 1];
  float a0 = 0.f, a1 = 0.f;
  int i = beg;
  for (; i + 8 <= end; i += 8) {
    int id[8];
    float w[8];
    unsigned int v[8];
#pragma unroll
    for (int q = 0; q < 8; ++q) id[q] = ids[i + q];
#pragma unroll
    for (int q = 0; q < 8; ++q) w[q] = fw[i + q];
#pragma unroll
    for (int q = 0; q < 8; ++q) v[q] = embb[(long)id[q] * 64 + u];
#pragma unroll
    for (int q = 0; q < 8; ++q) {
      a0 += w[q] * bf2f((unsigned short)(v[q] & 0xffffu));
      a1 += w[q] * bf2f((unsigned short)(v[q] >> 16));
    }
  }
  for (; i < end; ++i) {
    unsigned int v = embb[(long)ids[i] * 64 + u];
    float w = fw[i];
    a0 += w * bf2f((unsigned short)(v & 0xffffu));
    a1 += w * bf2f((unsigned short)(v >> 16));
  }
  a0 += bias[2 * u];
  a1 += bias[2 * u + 1];
  a0 = a0 > 0.f ? a0 : 0.f;
  a1 = a1 > 0.f ? a1 : 0.f;
  hb[(long)node * 64 + u] = (unsigned int)f2bf(a0) | ((unsigned int)f2bf(a1) << 16);
}

// wave-per-node aggregate over bf16 h: lane u covers cols {2u,2u+1}.
// Sequential 16B edge records (broadcast), 8 independent 256B row gathers
// in flight.  f32 accumulate; agg/res written f32 (float2, coalesced).
__global__ void __launch_bounds__(256) aggregate_kernel(const unsigned int* __restrict__ hb,
                                                        const int* __restrict__ eoff,
                                                        const int4* __restrict__ edges,
                                                        float2* __restrict__ agg,
                                                        float2* __restrict__ res, int n_nodes) {
  int node = blockIdx.x * 4 + (threadIdx.x >> 6);
  if (node >= n_nodes) return;
  int u = threadIdx.x & 63;
  int beg = eoff[node], end = eoff[node + 1];
  float a0 = 0.f, a1 = 0.f, r0 = 0.f, r1 = 0.f;
  int j = beg;
  for (; j + 8 <= end; j += 8) {
    int4 e[8];
    unsigned int v[8];
#pragma unroll
    for (int q = 0; q < 8; ++q) e[q] = edges[j + q];
#pragma unroll
    for (int q = 0; q < 8; ++q) v[q] = hb[(long)e[q].x * 64 + u];
#pragma unroll
    for (int q = 0; q < 8; ++q) {
      float lo = bf2f((unsigned short)(v[q] & 0xffffu));
      float hi = bf2f((unsigned short)(v[q] >> 16));
      float wp = __builtin_bit_cast(float, e[q].y);
      float ws = __builtin_bit_cast(float, e[q].z);
      a0 += wp * lo; a1 += wp * hi;
      r0 += ws * lo; r1 += ws * hi;
    }
  }
  for (; j < end; ++j) {
    int4 e = edges[j];
    unsigned int v = hb[(long)e.x * 64 + u];
    float lo = bf2f((unsigned short)(v & 0xffffu));
    float hi = bf2f((unsigned short)(v >> 16));
    float wp = __builtin_bit_cast(float, e.y);
    float ws = __builtin_bit_cast(float, e.z);
    a0 += wp * lo; a1 += wp * hi;
    r0 += ws * lo; r1 += ws * hi;
  }
  agg[(long)node * 64 + u] = make_float2(a0, a1);
  res[(long)node * 64 + u] = make_float2(r0, r1);
}

// hout_bf[node][t] = bf16(relu(agg[node]@W + b)[t] + res[node][t]);
// W cached in LDS f32 (exact GEMM), bf16 only at the final store.
__global__ void __launch_bounds__(256) update_kernel(const float* __restrict__ agg,
                                                     const float* __restrict__ res,
                                                     const float* __restrict__ W,
                                                     const float* __restrict__ b,
                                                     unsigned short* __restrict__ hout,
                                                     int n_nodes) {
  __shared__ __align__(16) float sW[HID * HID];
  __shared__ float sx[2][HID];
  int t = threadIdx.x & (HID - 1);
  int sub = threadIdx.x >> 7;
  for (int i = threadIdx.x; i < HID * HID / 4; i += 256)
    ((float4*)sW)[i] = ((const float4*)W)[i];
  float bias = b[t];
  __syncthreads();
  for (int node0 = blockIdx.x * 2; node0 < n_nodes; node0 += gridDim.x * 2) {
    int node = node0 + sub;
    bool valid = node < n_nodes;
    if (valid) sx[sub][t] = agg[(long)node * HID + t];
    __syncthreads();
    if (valid) {
      float acc = 0.f;
#pragma unroll 16
      for (int k = 0; k < HID; ++k) acc += sx[sub][k] * sW[k * HID + t];
      float v = acc + bias;
      v = v > 0.f ? v : 0.f;
      hout[(long)node * HID + t] = f2bf(v + res[(long)node * HID + t]);
    }
    __syncthreads();
  }
}

// WoT[n][k] = bf16(Wo[k][n])
__global__ void transpose_wo_kernel(const float* __restrict__ Wo,
                                    unsigned short* __restrict__ WoT, int labels) {
  int idx = blockIdx.x * 256 + threadIdx.x;
  if (idx < labels * HID) {
    int n = idx >> 7, k = idx & (HID - 1);
    WoT[idx] = f2bf(Wo[(long)k * labels + n]);
  }
}

#define LDK 136  // padded LDS K-stride (shorts); 272B rows keep 16B alignment, break bank aliasing

// out[50000 x labels] = h @ Wo + bo, bf16 MFMA, f32 accumulate.
// block = 256 thr = 4 waves; block tile 64(M) x 80(N); full K=128 staged once.
// A (h) is already bf16 -> pure copy staging.
__global__ void __launch_bounds__(256) out_gemm_kernel(const unsigned short* __restrict__ hb,
                                                       const unsigned short* __restrict__ WoT,
                                                       const float* __restrict__ bo,
                                                       float* __restrict__ out,
                                                       int n_nodes, int labels) {
  __shared__ __align__(16) unsigned short sA[64 * LDK];
  __shared__ __align__(16) unsigned short sB[80 * LDK];
  int m0 = blockIdx.x * 64;
  int n0 = blockIdx.y * 80;
  int tid = threadIdx.x;

  // stage A: 64 rows x 128 cols of bf16 h
  for (int i = tid; i < 64 * 32; i += 256) {
    int r = i >> 5, c4 = i & 31;
    int row = m0 + r;
    if (row >= n_nodes) row = n_nodes - 1;  // clamp: loads valid, stores bounded later
    ushort4 v = ((const ushort4*)(hb + (long)row * HID))[c4];
    *(ushort4*)&sA[r * LDK + c4 * 4] = v;
  }
  // stage B: 80 rows (n) x 128 cols (k) of WoT (already bf16)
  for (int i = tid; i < 80 * 32; i += 256) {
    int r = i >> 5, c4 = i & 31;
    ushort4 v = ((const ushort4*)(WoT + (long)(n0 + r) * HID))[c4];
    *(ushort4*)&sB[r * LDK + c4 * 4] = v;
  }
  __syncthreads();

  int wave = tid >> 6, lane = tid & 63;
  int lrow = lane & 15, quad = lane >> 4;
  f32x4 acc[5];
#pragma unroll
  for (int c = 0; c < 5; ++c) acc[c] = (f32x4){0.f, 0.f, 0.f, 0.f};

#pragma unroll
  for (int kk = 0; kk < 4; ++kk) {
    bf16x8 af = *(const bf16x8*)&sA[(wave * 16 + lrow) * LDK + kk * 32 + quad * 8];
#pragma unroll
    for (int c = 0; c < 5; ++c) {
      bf16x8 bf = *(const bf16x8*)&sB[(c * 16 + lrow) * LDK + kk * 32 + quad * 8];
      acc[c] = __builtin_amdgcn_mfma_f32_16x16x32_bf16(af, bf, acc[c], 0, 0, 0);
    }
  }

  // epilogue: D mapping col = lane&15, row = quad*4 + reg
#pragma unroll
  for (int c = 0; c < 5; ++c) {
    int n = n0 + c * 16 + lrow;
    float bias = bo[n];
#pragma unroll
    for (int r = 0; r < 4; ++r) {
      int m = m0 + wave * 16 + quad * 4 + r;
      if (m < n_nodes) out[(long)m * labels + n] = acc[c][r] + bias;
    }
  }
}

extern "C" void kernel_launch(void* const* d_in, const int* in_sizes, int n_in,
                              void* d_out, int out_size, void* d_ws, size_t ws_size,
                              hipStream_t stream) {
  const int* feat_ids = (const int*)d_in[0];
  const int* offsets = (const int*)d_in[1];
  const float* feat_w = (const float*)d_in[2];
  const int* esrc = (const int*)d_in[3];
  const int* edst = (const int*)d_in[4];
  const float* ppi = (const float*)d_in[5];
  const float* selfw = (const float*)d_in[6];
  const float* emb = (const float*)d_in[7];
  const float* ibias = (const float*)d_in[8];
  const float* W1 = (const float*)d_in[9];
  const float* b1 = (const float*)d_in[10];
  const float* W2 = (const float*)d_in[11];
  const float* b2 = (const float*)d_in[12];
  const float* Wo = (const float*)d_in[13];
  const float* bo = (const float*)d_in[14];
  float* out = (float*)d_out;

  int N = in_sizes[1] - 1;       // 50000
  int E = in_sizes[3];           // 1600000
  int EMBN = in_sizes[7];        // VOCAB*HID
  int LABELS = in_sizes[14];     // 2000

  char* ws = (char*)d_ws;
  size_t HN = (size_t)N * HID;
  unsigned short* h_bf = (unsigned short*)ws;  ws += HN * 2;                 // bf16 h
  float* agg = (float*)ws;                     ws += HN * 4;
  float* res = (float*)ws;                     ws += HN * 4;
  unsigned short* WoT = (unsigned short*)ws;   ws += (size_t)LABELS * HID * 2;
  unsigned short* embb = (unsigned short*)ws;  ws += (size_t)EMBN * 2;       // bf16 emb
  int4* edges = (int4*)ws;                     ws += (size_t)E * 16;         // 16B-aligned
  int* deg = (int*)ws;                         ws += (size_t)N * 4;
  int* eoff = (int*)ws;                        ws += (size_t)(N + 1) * 4;
  int* cursor = (int*)ws;                      ws += (size_t)N * 4;

  // build dst-CSR with payload sorted in place (reused by both layers)
  zero_int_kernel<<<(N + 255) / 256, 256, 0, stream>>>(deg, N);
  degree_kernel<<<(E + 255) / 256, 256, 0, stream>>>(edst, deg, E);
  scan_kernel<<<1, 1024, 0, stream>>>(deg, eoff, N);
  copy_int_kernel<<<(N + 255) / 256, 256, 0, stream>>>(eoff, cursor, N);
  scatter_kernel<<<(E + 255) / 256, 256, 0, stream>>>(edst, esrc, ppi, selfw,
                                                      cursor, edges, E);

  // input layer
  cast_emb_kernel<<<(EMBN + 255) / 256, 256, 0, stream>>>(emb, embb, EMBN);
  embed_kernel<<<(N + 3) / 4, 256, 0, stream>>>(feat_ids, offsets, feat_w,
                                                (const unsigned int*)embb, ibias,
                                                (unsigned int*)h_bf, N);
  transpose_wo_kernel<<<(LABELS * HID + 255) / 256, 256, 0, stream>>>(Wo, WoT, LABELS);

  // GCN layer 1
  aggregate_kernel<<<(N + 3) / 4, 256, 0, stream>>>((const unsigned int*)h_bf, eoff, edges,
                                                    (float2*)agg, (float2*)res, N);
  update_kernel<<<1024, 256, 0, stream>>>(agg, res, W1, b1, h_bf, N);
  // GCN layer 2
  aggregate_kernel<<<(N + 3) / 4, 256, 0, stream>>>((const unsigned int*)h_bf, eoff, edges,
                                                    (float2*)agg, (float2*)res, N);
  update_kernel<<<1024, 256, 0, stream>>>(agg, res, W2, b2, h_bf, N);

  // output layer
  dim3 g((N + 63) / 64, LABELS / 80);
  out_gemm_kernel<<<g, 256, 0, stream>>>(h_bf, WoT, bo, out, N, LABELS);
}